// Round 1
// 167.342 us; speedup vs baseline: 1.2485x; 1.2485x over previous
//
#include <hip/hip_runtime.h>

#define DIMK 64
#define MC 256
#define RPB 128                  // rows per block
#define NROWS 262144
#define NB (NROWS / RPB)         // 2048 blocks

typedef _Float16 half8 __attribute__((ext_vector_type(8)));
typedef _Float16 half4 __attribute__((ext_vector_type(4)));
typedef _Float16 half2v __attribute__((ext_vector_type(2)));
typedef float f32x16 __attribute__((ext_vector_type(16)));

// LDS byte offsets (64 KiB total, dynamic)
#define ZH_OFF 0        // [128][64] f16, 8x16B chunks/row, chunk ^= (row&7)
#define ZL_OFF 16384
#define AH_OFF 32768    // [256][32] f16 (one K-half), 4x16B chunks/row, swizzled
#define AL_OFF 49152
#define LDS_BYTES 65536

// tiny pre-kernel: cvec[t] = pivot @ At[:,t]  (fp32, matches reference denom path)
__global__ void precompute_c(const float* __restrict__ pivot,
                             const float* __restrict__ At,
                             float* __restrict__ cvec) {
    const int t = threadIdx.x;
    float acc = 0.f;
#pragma unroll
    for (int k = 0; k < DIMK; ++k) acc = fmaf(pivot[k], At[k * MC + t], acc);
    cvec[t] = acc;
}

__global__ __launch_bounds__(256, 2)
void fused_constrain_mfma(const float* __restrict__ z,
                          const float* __restrict__ pivot,
                          const float* __restrict__ At,
                          const float* __restrict__ b,
                          const float* __restrict__ cvec,
                          float* __restrict__ out) {
    extern __shared__ char lds[];
    const int tid  = threadIdx.x;
    const int lane = tid & 63;
    const int li   = lane & 31;      // col-in-tile / row-in-tile lane id
    const int hi   = lane >> 5;      // half-wave (k-group)
    const int R0   = (tid >> 6) * 32;            // wave's row base (0..96)
    const int base = blockIdx.x * (RPB * DIMK);  // block's z/out base (floats)

    // ---- stage z tile: 128x64 fp32 -> zh/zl fp16, chunk-XOR swizzled ----
    {
        const float4* __restrict__ src = (const float4*)(z + base);
#pragma unroll
        for (int p = 0; p < 8; ++p) {
            const int f  = p * 256 + tid;   // float4 index 0..2047
            const int r  = f >> 4;          // row 0..127
            const int c4 = f & 15;          // float4-col within row
            const float4 v = src[f];
            half4 h, l;
            h[0] = (_Float16)v.x; l[0] = (_Float16)(v.x - (float)h[0]);
            h[1] = (_Float16)v.y; l[1] = (_Float16)(v.y - (float)h[1]);
            h[2] = (_Float16)v.z; l[2] = (_Float16)(v.z - (float)h[2]);
            h[3] = (_Float16)v.w; l[3] = (_Float16)(v.w - (float)h[3]);
            const int bo = r * 128 + (((c4 >> 1) ^ (r & 7)) << 4) + ((c4 & 1) << 3);
            *(half4*)(lds + ZH_OFF + bo) = h;
            *(half4*)(lds + ZL_OFF + bo) = l;
        }
    }

    // ---- stage one K-half (32 k) of At^T as fp16 hi/lo, swizzled ----
    auto stage_at = [&](const int ph) {
        const int n  = tid;          // column 0..255
        const int kb = ph * 32;
#pragma unroll
        for (int kc = 0; kc < 4; ++kc) {     // 4 chunks of 8 k
            float v[8];
#pragma unroll
            for (int j = 0; j < 8; ++j)
                v[j] = At[(kb + kc * 8 + j) * MC + n];   // coalesced across threads
            half8 h, l;
#pragma unroll
            for (int j = 0; j < 8; ++j) {
                h[j] = (_Float16)v[j];
                l[j] = (_Float16)(v[j] - (float)h[j]);
            }
            const int bo = n * 64 + ((kc ^ (n & 3) ^ ((n >> 2) & 3)) << 4);
            *(half8*)(lds + AH_OFF + bo) = h;
            *(half8*)(lds + AL_OFF + bo) = l;
        }
    };

    f32x16 acc[8];
#pragma unroll
    for (int ct = 0; ct < 8; ++ct)
#pragma unroll
        for (int e = 0; e < 16; ++e) acc[ct][e] = 0.f;

    stage_at(0);
    __syncthreads();

    const int rowA = R0 + li;            // A-fragment row (lane&31)
    const int zrb  = rowA * 128;
    const int sA   = rowA & 7;
    const int nx   = (li & 3) ^ ((li >> 2) & 3);   // B chunk swizzle (ct-independent)

    // 3-product split GEMM over one K-half: S += zh@ah + zh@al + zl@ah
    auto compute2 = [&](const int ksBase) {
#pragma unroll
        for (int ksl = 0; ksl < 2; ++ksl) {
            const int ks = ksBase + ksl;
            const int ca = ((ks * 2 + hi) ^ sA) << 4;
            const half8 azh = *(const half8*)(lds + ZH_OFF + zrb + ca);
            const half8 azl = *(const half8*)(lds + ZL_OFF + zrb + ca);
            const int cb = ((ksl * 2 + hi) ^ nx) << 4;
#pragma unroll
            for (int ct = 0; ct < 8; ++ct) {
                const int n = ct * 32 + li;
                const half8 bh = *(const half8*)(lds + AH_OFF + n * 64 + cb);
                const half8 bl = *(const half8*)(lds + AL_OFF + n * 64 + cb);
                acc[ct] = __builtin_amdgcn_mfma_f32_32x32x16_f16(azh, bh, acc[ct], 0, 0, 0);
                acc[ct] = __builtin_amdgcn_mfma_f32_32x32x16_f16(azh, bl, acc[ct], 0, 0, 0);
                acc[ct] = __builtin_amdgcn_mfma_f32_32x32x16_f16(azl, bh, acc[ct], 0, 0, 0);
            }
        }
    };

    compute2(0);
    __syncthreads();      // done reading At K-half 0
    stage_at(1);
    __syncthreads();
    compute2(2);

    // ---- epilogue: masked alpha, row-max over 256 cols, rescale, store ----
    float bv[8], cv[8];
#pragma unroll
    for (int ct = 0; ct < 8; ++ct) {
        bv[ct] = b[ct * 32 + li];
        cv[ct] = cvec[ct * 32 + li];
    }
    float gm[16];
#pragma unroll
    for (int r = 0; r < 16; ++r) gm[r] = 0.f;
#pragma unroll
    for (int ct = 0; ct < 8; ++ct)
#pragma unroll
        for (int r = 0; r < 16; ++r) {
            const float s  = acc[ct][r];
            const float sa = s - bv[ct];
            const float q  = fmaxf(s - cv[ct], 1e-9f);
            // sa<0 -> negative alpha, excluded by fmax against gm>=0
            gm[r] = fmaxf(gm[r], sa * __builtin_amdgcn_rcpf(q));
        }
    // reduce over the 32 col-lanes (bits 0..4; stays within hi-half)
#pragma unroll
    for (int r = 0; r < 16; ++r)
#pragma unroll
        for (int off = 1; off < 32; off <<= 1)
            gm[r] = fmaxf(gm[r], __shfl_xor(gm[r], off));

    const float pv0 = pivot[2 * li];
    const float pv1 = pivot[2 * li + 1];
#pragma unroll
    for (int r = 0; r < 16; ++r) {
        const int rl  = (r & 3) + ((r >> 2) << 3) + (hi << 2);  // C/D row map
        const int row = R0 + rl;
        const int zb  = row * 128 + (((li >> 2) ^ (row & 7)) << 4) + ((li & 3) << 2);
        const half2v h2 = *(const half2v*)(lds + ZH_OFF + zb);
        const half2v l2 = *(const half2v*)(lds + ZL_OFF + zb);
        const float z0 = (float)h2[0] + (float)l2[0];
        const float z1 = (float)h2[1] + (float)l2[1];
        const float g  = gm[r];
        float2 o;
        o.x = fmaf(g, pv0 - z0, z0);
        o.y = fmaf(g, pv1 - z1, z1);
        *(float2*)(out + base + row * 64 + 2 * li) = o;
    }
}

extern "C" void kernel_launch(void* const* d_in, const int* in_sizes, int n_in,
                              void* d_out, int out_size, void* d_ws, size_t ws_size,
                              hipStream_t stream) {
    const float* z     = (const float*)d_in[0];
    const float* pivot = (const float*)d_in[1];
    const float* At    = (const float*)d_in[2];
    const float* b     = (const float*)d_in[3];
    float* cvec = (float*)d_ws;   // 256 floats of scratch
    precompute_c<<<dim3(1), dim3(MC), 0, stream>>>(pivot, At, cvec);
    fused_constrain_mfma<<<dim3(NB), dim3(256), LDS_BYTES, stream>>>(
        z, pivot, At, b, cvec, (float*)d_out);
}

// Round 3
// 152.644 us; speedup vs baseline: 1.3688x; 1.0963x over previous
//
#include <hip/hip_runtime.h>

#define DIMK 64
#define MC 256
#define BR 64                    // rows per block
#define NROWS 262144
#define NB (NROWS / BR)          // 4096 blocks

// workspace layout (bytes):
//   [0, 1024)            cvec fp32 (256 floats)            [always]
//   [1024, 1024+65536)   At fp16 hi/lo image (fast path only, guarded by ws_size):
//     step s in {0,1}: AH_s at 1024+s*32768, AL_s at +16384
//     within segment: col n holds 32 k's as 4 chunks of half8 at
//     byte n*64 + ((kc ^ swz(n))<<4), swz(n) = (n&3)^((n>>2)&3)
#define WS_AT 1024
#define WS_NEED (1024 + 65536)

#define LDS_AH 0
#define LDS_AL 16384
#define LDS_GM 32768             // [2 rg][32 row][2 cg] floats = 512 B

typedef _Float16 half8 __attribute__((ext_vector_type(8)));
typedef float f32x16 __attribute__((ext_vector_type(16)));

// cvec only (1 KB ws — proven-safe footprint)
__global__ void precompute_c(const float* __restrict__ pivot,
                             const float* __restrict__ At,
                             float* __restrict__ ws) {
    const int t = threadIdx.x;
    float acc = 0.f;
#pragma unroll
    for (int k = 0; k < DIMK; ++k) acc = fmaf(pivot[k], At[k * MC + t], acc);
    ws[t] = acc;
}

// cvec + one-time At -> fp16 hi/lo split, pre-swizzled (fast path)
__global__ void precompute_at(const float* __restrict__ pivot,
                              const float* __restrict__ At,
                              float* __restrict__ ws) {
    const int t = threadIdx.x;              // column 0..255
    const int swz = (t & 3) ^ ((t >> 2) & 3);
    float col[DIMK];
    float acc = 0.f;
#pragma unroll
    for (int k = 0; k < DIMK; ++k) {
        col[k] = At[k * MC + t];            // coalesced across t
        acc = fmaf(pivot[k], col[k], acc);
    }
    ws[t] = acc;                            // cvec, fp32
    char* wsb = (char*)ws;
#pragma unroll
    for (int s = 0; s < 2; ++s) {
#pragma unroll
        for (int kc = 0; kc < 4; ++kc) {
            half8 h, l;
#pragma unroll
            for (int j = 0; j < 8; ++j) {
                const float v = col[s * 32 + kc * 8 + j];
                h[j] = (_Float16)v;
                l[j] = (_Float16)(v - (float)h[j]);
            }
            const int off = t * 64 + ((kc ^ swz) << 4);
            *(half8*)(wsb + WS_AT + s * 32768 + off) = h;
            *(half8*)(wsb + WS_AT + s * 32768 + 16384 + off) = l;
        }
    }
}

template <bool PREAT>
__global__ __launch_bounds__(256, 4)
void fused_constrain_mfma(const float* __restrict__ z,
                          const float* __restrict__ pivot,
                          const float* __restrict__ At,
                          const float* __restrict__ b,
                          const float* __restrict__ ws,
                          float* __restrict__ out) {
    __shared__ __align__(16) char lds[33280];

    const int tid  = threadIdx.x;
    const int lane = tid & 63;
    const int li   = lane & 31;          // tile col lane (B) / tile row (A)
    const int hi   = lane >> 5;          // k-half within 16-k step
    const int wid  = tid >> 6;
    const int rg   = wid >> 1;           // row group: rows rg*32..+32
    const int cg   = wid & 1;            // col group: cols cg*128..+128
    const int R0   = rg * 32;
    const int colbase = cg * 128;
    const int swz  = (li & 3) ^ ((li >> 2) & 3);
    const int base = blockIdx.x * (BR * DIMK);

    // stage one 32-k step of At (hi/lo fp16, swizzled) into LDS
    auto stage_at = [&](const int s) {
        if constexpr (PREAT) {
            const char* wsA = (const char*)ws + WS_AT + s * 32768;
#pragma unroll
            for (int p = 0; p < 8; ++p) {
                const int f = p * 256 + tid;
                *(float4*)(lds + f * 16) = *(const float4*)(wsA + f * 16);
            }
        } else {
            const int swzT = (tid & 3) ^ ((tid >> 2) & 3);
#pragma unroll
            for (int kc = 0; kc < 4; ++kc) {
                float v[8];
#pragma unroll
                for (int j = 0; j < 8; ++j)
                    v[j] = At[(s * 32 + kc * 8 + j) * MC + tid];  // coalesced
                half8 h, l;
#pragma unroll
                for (int j = 0; j < 8; ++j) {
                    h[j] = (_Float16)v[j];
                    l[j] = (_Float16)(v[j] - (float)h[j]);
                }
                const int off = tid * 64 + ((kc ^ swzT) << 4);
                *(half8*)(lds + LDS_AH + off) = h;
                *(half8*)(lds + LDS_AL + off) = l;
            }
        }
    };

    // ---- issue z A-fragment loads early (rows owned per-lane, both k-steps) ----
    float4 zf[8];
    {
        const float* zr = z + base + (R0 + li) * DIMK + hi * 8;
#pragma unroll
        for (int q = 0; q < 4; ++q) {            // q = s*2 + ksl
            const float* p = zr + (q >> 1) * 32 + (q & 1) * 16;
            zf[q * 2 + 0] = *(const float4*)(p);
            zf[q * 2 + 1] = *(const float4*)(p + 4);
        }
    }

    stage_at(0);

    // ---- convert z to fp16 hi/lo fragments (hides under staging) ----
    half8 azh[4], azl[4];
    const float* zv = (const float*)zf;
#pragma unroll
    for (int q = 0; q < 4; ++q)
#pragma unroll
        for (int j = 0; j < 8; ++j) {
            const float v = zv[q * 8 + j];
            azh[q][j] = (_Float16)v;
            azl[q][j] = (_Float16)(v - (float)azh[q][j]);
        }

    f32x16 acc[4];
#pragma unroll
    for (int ct = 0; ct < 4; ++ct)
#pragma unroll
        for (int e = 0; e < 16; ++e) acc[ct][e] = 0.f;

    __syncthreads();

    // ---- compute step 0: S += zh@ah + zh@al + zl@ah over k 0..31 ----
#pragma unroll
    for (int ksl = 0; ksl < 2; ++ksl) {
        const int cb = ((ksl * 2 + hi) ^ swz) << 4;
        const half8 ah = azh[ksl], al = azl[ksl];
#pragma unroll
        for (int ct = 0; ct < 4; ++ct) {
            const int off = (colbase + ct * 32 + li) * 64 + cb;
            const half8 bh = *(const half8*)(lds + LDS_AH + off);
            const half8 bl = *(const half8*)(lds + LDS_AL + off);
            acc[ct] = __builtin_amdgcn_mfma_f32_32x32x16_f16(ah, bh, acc[ct], 0, 0, 0);
            acc[ct] = __builtin_amdgcn_mfma_f32_32x32x16_f16(ah, bl, acc[ct], 0, 0, 0);
            acc[ct] = __builtin_amdgcn_mfma_f32_32x32x16_f16(al, bh, acc[ct], 0, 0, 0);
        }
    }
    __syncthreads();

    stage_at(1);
    __syncthreads();

    // ---- compute step 1: k 32..63 ----
#pragma unroll
    for (int ksl = 0; ksl < 2; ++ksl) {
        const int cb = ((ksl * 2 + hi) ^ swz) << 4;
        const half8 ah = azh[2 + ksl], al = azl[2 + ksl];
#pragma unroll
        for (int ct = 0; ct < 4; ++ct) {
            const int off = (colbase + ct * 32 + li) * 64 + cb;
            const half8 bh = *(const half8*)(lds + LDS_AH + off);
            const half8 bl = *(const half8*)(lds + LDS_AL + off);
            acc[ct] = __builtin_amdgcn_mfma_f32_32x32x16_f16(ah, bh, acc[ct], 0, 0, 0);
            acc[ct] = __builtin_amdgcn_mfma_f32_32x32x16_f16(ah, bl, acc[ct], 0, 0, 0);
            acc[ct] = __builtin_amdgcn_mfma_f32_32x32x16_f16(al, bh, acc[ct], 0, 0, 0);
        }
    }

    // ---- epilogue: masked alpha, intra-wave col-max, cross-wave combine ----
    float bv[4], cv[4];
#pragma unroll
    for (int ct = 0; ct < 4; ++ct) {
        const int c = colbase + ct * 32 + li;
        bv[ct] = b[c];
        cv[ct] = ws[c];                 // cvec (fp32)
    }
    float gm[16];
#pragma unroll
    for (int r = 0; r < 16; ++r) gm[r] = 0.f;
#pragma unroll
    for (int ct = 0; ct < 4; ++ct)
#pragma unroll
        for (int r = 0; r < 16; ++r) {
            const float sv = acc[ct][r];
            const float sa = sv - bv[ct];
            const float qd = fmaxf(sv - cv[ct], 1e-9f);
            // sa<0 gives negative alpha, excluded by fmax against gm>=0
            gm[r] = fmaxf(gm[r], sa * __builtin_amdgcn_rcpf(qd));
        }
#pragma unroll
    for (int r = 0; r < 16; ++r)
#pragma unroll
        for (int off = 1; off < 32; off <<= 1)   // reduce over 32 col-lanes
            gm[r] = fmaxf(gm[r], __shfl_xor(gm[r], off));

    float* gmbuf = (float*)(lds + LDS_GM);
#pragma unroll
    for (int r = 0; r < 16; ++r) {
        const int row = (r & 3) + 8 * (r >> 2) + 4 * hi;   // C/D row map
        if (li == 0) gmbuf[rg * 64 + row * 2 + cg] = gm[r];
    }
    __syncthreads();

    // cg0 stores rows R0+0..15 (its r 0..7), cg1 stores rows R0+16..31
    const float2 p2 = *(const float2*)(pivot + 2 * li);
    const int r0 = cg * 8;
#pragma unroll
    for (int rr = 0; rr < 8; ++rr) {
        const int r   = r0 + rr;
        const int row = (r & 3) + 8 * (r >> 2) + 4 * hi;
        const float g = fmaxf(gm[r], gmbuf[rg * 64 + row * 2 + (cg ^ 1)]);
        const int idx = base + (R0 + row) * DIMK + 2 * li;
        const float2 zz = *(const float2*)(z + idx);   // exact fp32 z, L1-hot
        float2 o;
        o.x = fmaf(g, p2.x - zz.x, zz.x);
        o.y = fmaf(g, p2.y - zz.y, zz.y);
        *(float2*)(out + idx) = o;
    }
}

extern "C" void kernel_launch(void* const* d_in, const int* in_sizes, int n_in,
                              void* d_out, int out_size, void* d_ws, size_t ws_size,
                              hipStream_t stream) {
    const float* z     = (const float*)d_in[0];
    const float* pivot = (const float*)d_in[1];
    const float* At    = (const float*)d_in[2];
    const float* b     = (const float*)d_in[3];
    float* ws = (float*)d_ws;
    if (ws_size >= (size_t)WS_NEED) {
        // fast path: pre-split At image lives in workspace
        precompute_at<<<dim3(1), dim3(MC), 0, stream>>>(pivot, At, ws);
        fused_constrain_mfma<true><<<dim3(NB), dim3(256), 0, stream>>>(
            z, pivot, At, b, ws, (float*)d_out);
    } else {
        // safe path: only 1 KB of workspace (cvec); At split done per-block
        precompute_c<<<dim3(1), dim3(MC), 0, stream>>>(pivot, At, ws);
        fused_constrain_mfma<false><<<dim3(NB), dim3(256), 0, stream>>>(
            z, pivot, At, b, ws, (float*)d_out);
    }
}